// Round 5
// baseline (340.427 us; speedup 1.0000x reference)
//
#include <hip/hip_runtime.h>
#include <hip/hip_bf16.h>

#define HIDDEN 4096
#define INTER 11008
#define MTOK 128  // 4*32 tokens

typedef float f32x4 __attribute__((ext_vector_type(4)));
typedef short s16x8 __attribute__((ext_vector_type(8)));
typedef __attribute__((address_space(3))) unsigned int as3_u32;
typedef __attribute__((address_space(1))) unsigned int as1_u32;

__device__ __forceinline__ unsigned short f2bf(float f) {
    unsigned int u = __float_as_uint(f);
    u += 0x7FFFu + ((u >> 16) & 1u);
    return (unsigned short)(u >> 16);
}

__device__ __forceinline__ s16x8 cvt8(f32x4 a, f32x4 b) {
    s16x8 r;
    r[0] = (short)f2bf(a[0]); r[1] = (short)f2bf(a[1]);
    r[2] = (short)f2bf(a[2]); r[3] = (short)f2bf(a[3]);
    r[4] = (short)f2bf(b[0]); r[5] = (short)f2bf(b[1]);
    r[6] = (short)f2bf(b[2]); r[7] = (short)f2bf(b[3]);
    return r;
}

// ---------------- kernel 1: x fp32 -> bf16 in MFMA FRAGMENT ORDER ----------------
// Group g = ((s64*8 + mt)*2 + kk2)*64 + lane holds 8 bf16:
//   x[mt*16 + (lane&15)][s64*64 + kk2*32 + (lane>>4)*8 + e]
__global__ __launch_bounds__(256) void k_convert_x2(const float* __restrict__ x,
                                                    s16x8* __restrict__ xf) {
    int t = blockIdx.x * 256 + threadIdx.x;  // [0, 65536)
    int lane = t & 63, kk2 = (t >> 6) & 1, mt = (t >> 7) & 7, s64 = t >> 10;
    int row = mt * 16 + (lane & 15);
    int k0 = s64 * 64 + kk2 * 32 + (lane >> 4) * 8;
    const float* p = x + (size_t)row * HIDDEN + k0;
    f32x4 a = *reinterpret_cast<const f32x4*>(p);
    f32x4 b = *reinterpret_cast<const f32x4*>(p + 4);
    xf[t] = cvt8(a, b);
}

// per-wave weight DMA: 16 rows x 256 f32; ONE instr per row = 1KB contiguous HBM.
// XOR(j&7)<<4 swizzle on the GLOBAL SOURCE lane index (LDS dest linear).
__device__ __forceinline__ void dma_w16(const float* __restrict__ w, size_t ldk,
                                        int row0, int lane, int k0, float* dst) {
#pragma unroll
    for (int j = 0; j < 16; ++j) {
        const float* src = w + (size_t)(row0 + j) * ldk + k0 + ((lane ^ (j & 7)) << 2);
        __builtin_amdgcn_global_load_lds((as1_u32*)src, (as3_u32*)(dst + j * 256), 16, 0, 0);
    }
}

// core: wave owns 16 weight rows; K_STEP=256; double-buffered LDS (2x16KB/wave);
// counted vmcnt(16) keeps next step's 16KB in flight; A from frag-ordered buffer.
template <int LDK>
__device__ __forceinline__ void gemm_core(const s16x8* __restrict__ afb,
                                          const float* __restrict__ w, int row0,
                                          int sbeg, int send, f32x4 acc[8],
                                          float* wbuf) {
    const int lane = threadIdx.x & 63;
    const int r16 = lane & 15, g4 = lane >> 4;

    dma_w16(w, LDK, row0, lane, sbeg * 256, wbuf);

    for (int s = sbeg; s < send; ++s) {
        const int buf = (s - sbeg) & 1;
        if (s + 1 < send) {
            dma_w16(w, LDK, row0, lane, (s + 1) * 256, wbuf + (buf ^ 1) * 4096);
            asm volatile("s_waitcnt vmcnt(16)" ::: "memory");  // step s landed
        } else {
            asm volatile("s_waitcnt vmcnt(0)" ::: "memory");
        }
        __builtin_amdgcn_s_barrier();  // raw: align waves for L1 A-reuse (no LDS dep)
        const char* wrow = (const char*)(wbuf + buf * 4096 + r16 * 256);
        const unsigned swz = (unsigned)((r16 & 7) << 4);
#pragma unroll
        for (int q = 0; q < 4; ++q) {
#pragma unroll
            for (int kk2 = 0; kk2 < 2; ++kk2) {
                unsigned X = q * 256 + kk2 * 128 + g4 * 32;
                f32x4 b0 = *reinterpret_cast<const f32x4*>(wrow + (X ^ swz));
                f32x4 b1 = *reinterpret_cast<const f32x4*>(wrow + ((X + 16) ^ swz));
                s16x8 bf = cvt8(b0, b1);
                const s16x8* ab = afb + (size_t)(((s * 4 + q) * 16 + kk2) * 64 + lane);
#pragma unroll
                for (int mt = 0; mt < 8; ++mt) {
                    s16x8 av = ab[mt * 128];
                    acc[mt] = __builtin_amdgcn_mfma_f32_16x16x32_bf16(av, bf, acc[mt], 0, 0, 0);
                }
            }
        }
    }
}

// ---------------- kernel 2: gate & up GEMM ----------------
// grid.x = 344 * 2 * Sg ; block = 128 (2 waves). Wave owns 16 weight rows.
__global__ __launch_bounds__(128) void k_gateup5(const s16x8* __restrict__ xf,
                                                 const float* __restrict__ wg,
                                                 const float* __restrict__ wu,
                                                 float* __restrict__ pg,
                                                 float* __restrict__ pu, int Sg) {
    __shared__ __align__(16) float wlds[2][2][16 * 256];  // [wave][buf] = 64 KB
    const int wv = threadIdx.x >> 6;
    const int gid = blockIdx.x;
    const int nt = gid % 344, rest = gid / 344;
    const int mat = rest & 1, kc = rest >> 1;
    const int n0 = nt * 32;
    const int nsteps = 16 / Sg;  // (HIDDEN/256)/Sg
    const int sbeg = kc * nsteps, send = sbeg + nsteps;

    f32x4 acc[8];
#pragma unroll
    for (int i = 0; i < 8; ++i) acc[i] = (f32x4)0.0f;

    gemm_core<HIDDEN>(xf, mat ? wu : wg, n0 + wv * 16, sbeg, send, acc, &wlds[wv][0][0]);

    const int lane = threadIdx.x & 63, r16 = lane & 15, g4 = lane >> 4;
    float* p = (mat ? pu : pg) + (size_t)kc * (MTOK * INTER);
#pragma unroll
    for (int mt = 0; mt < 8; ++mt)
#pragma unroll
        for (int r = 0; r < 4; ++r) {
            int m = mt * 16 + g4 * 4 + r;
            p[(size_t)m * INTER + n0 + wv * 16 + r16] = acc[mt][r];
        }
}

// ---------------- kernel 3: combine + silu*up -> h in FRAG ORDER (bf16) ----------
// thread t -> group fields; writes hf[t] (16B). grid = 688 x 256.
__global__ __launch_bounds__(256) void k_combine2(const float* __restrict__ pg,
                                                  const float* __restrict__ pu,
                                                  s16x8* __restrict__ hf, int Sg) {
    int t = blockIdx.x * 256 + threadIdx.x;  // [0, 176128)
    int lane = t & 63, r16 = lane & 15, g4 = (lane >> 4) & 3;
    int kk2 = (t >> 6) & 1, mt = (t >> 7) & 7, s64 = t >> 10;
    int m = mt * 16 + r16;
    size_t base = (size_t)m * INTER + s64 * 64 + kk2 * 32 + g4 * 8;

    f32x4 g0 = (f32x4)0.0f, g1 = (f32x4)0.0f, u0 = (f32x4)0.0f, u1 = (f32x4)0.0f;
    for (int c = 0; c < Sg; ++c) {
        const float* pgc = pg + (size_t)c * (MTOK * INTER) + base;
        const float* puc = pu + (size_t)c * (MTOK * INTER) + base;
        g0 += *reinterpret_cast<const f32x4*>(pgc);
        g1 += *reinterpret_cast<const f32x4*>(pgc + 4);
        u0 += *reinterpret_cast<const f32x4*>(puc);
        u1 += *reinterpret_cast<const f32x4*>(puc + 4);
    }
    f32x4 h0, h1;
#pragma unroll
    for (int e = 0; e < 4; ++e) {
        h0[e] = g0[e] / (1.0f + __expf(-g0[e])) * u0[e];
        h1[e] = g1[e] / (1.0f + __expf(-g1[e])) * u1[e];
    }
    hf[t] = cvt8(h0, h1);
}

// ---------------- kernel 4: down GEMM ----------------
// grid.x = 128 * Sd ; block = 128 (2 waves). K-steps [0,43) split across Sd.
__global__ __launch_bounds__(128) void k_down5(const s16x8* __restrict__ hf,
                                               const float* __restrict__ wd,
                                               float* __restrict__ pd, int Sd) {
    __shared__ __align__(16) float wlds[2][2][16 * 256];
    const int wv = threadIdx.x >> 6;
    const int gid = blockIdx.x;
    const int nt = gid % 128, kc = gid / 128;
    const int n0 = nt * 32;
    const int sbeg = (43 * kc) / Sd, send = (43 * (kc + 1)) / Sd;

    f32x4 acc[8];
#pragma unroll
    for (int i = 0; i < 8; ++i) acc[i] = (f32x4)0.0f;

    gemm_core<INTER>(hf, wd, n0 + wv * 16, sbeg, send, acc, &wlds[wv][0][0]);

    const int lane = threadIdx.x & 63, r16 = lane & 15, g4 = lane >> 4;
    float* p = pd + (size_t)kc * (MTOK * HIDDEN);
#pragma unroll
    for (int mt = 0; mt < 8; ++mt)
#pragma unroll
        for (int r = 0; r < 4; ++r) {
            int m = mt * 16 + g4 * 4 + r;
            p[(size_t)m * HIDDEN + n0 + wv * 16 + r16] = acc[mt][r];
        }
}

// ---------------- kernel 5: reduce Sd partials -> out ----------------
__global__ __launch_bounds__(256) void k_reduce(const float* __restrict__ pd,
                                                float* __restrict__ out, int Sd) {
    int i = (blockIdx.x * 256 + threadIdx.x) * 4;
    const int NT = MTOK * HIDDEN;
    f32x4 s = (f32x4)0.0f;
    for (int c = 0; c < Sd; ++c)
        s += *reinterpret_cast<const f32x4*>(pd + (size_t)c * NT + i);
    *reinterpret_cast<f32x4*>(out + i) = s;
}

extern "C" void kernel_launch(void* const* d_in, const int* in_sizes, int n_in,
                              void* d_out, int out_size, void* d_ws, size_t ws_size,
                              hipStream_t stream) {
    const float* x  = (const float*)d_in[0];
    const float* wg = (const float*)d_in[1];
    const float* wu = (const float*)d_in[2];
    const float* wd = (const float*)d_in[3];
    float* out = (float*)d_out;

    const size_t XB = 1048576;                      // xf (frag-ordered x, bf16)
    const size_t HB = 2818048;                      // hf (frag-ordered h, bf16)
    const size_t PGU = (size_t)MTOK * INTER * 4;    // per split per matrix
    const size_t PD  = (size_t)MTOK * HIDDEN * 4;   // per split
    const int cfg[3][2] = {{2, 2}, {1, 2}, {1, 1}};
    int Sg = 1, Sd = 1;
    for (int c = 0; c < 3; ++c) {
        size_t need = XB + HB + 2 * (size_t)cfg[c][0] * PGU + (size_t)cfg[c][1] * PD;
        if (need <= ws_size) { Sg = cfg[c][0]; Sd = cfg[c][1]; break; }
    }

    char* ws = (char*)d_ws;
    s16x8* xf = (s16x8*)ws;
    s16x8* hf = (s16x8*)(ws + XB);
    float* pg = (float*)(ws + XB + HB);
    float* pu = pg + (size_t)Sg * (MTOK * INTER);
    float* pd = pu + (size_t)Sg * (MTOK * INTER);

    k_convert_x2<<<256, 256, 0, stream>>>(x, xf);
    k_gateup5<<<344 * 2 * Sg, 128, 0, stream>>>(xf, wg, wu, pg, pu, Sg);
    k_combine2<<<688, 256, 0, stream>>>(pg, pu, hf, Sg);
    k_down5<<<128 * Sd, 128, 0, stream>>>(hf, wd, pd, Sd);
    k_reduce<<<512, 256, 0, stream>>>(pd, out, Sd);
}

// Round 6
// 178.575 us; speedup vs baseline: 1.9064x; 1.9064x over previous
//
#include <hip/hip_runtime.h>
#include <hip/hip_bf16.h>

#define HIDDEN 4096
#define INTER 11008
#define MTOK 128  // 4*32 tokens

typedef float f32x4 __attribute__((ext_vector_type(4)));
typedef short s16x8 __attribute__((ext_vector_type(8)));
typedef __attribute__((address_space(3))) unsigned int as3_u32;
typedef __attribute__((address_space(1))) unsigned int as1_u32;

__device__ __forceinline__ unsigned short f2bf(float f) {
    unsigned int u = __float_as_uint(f);
    u += 0x7FFFu + ((u >> 16) & 1u);
    return (unsigned short)(u >> 16);
}

__device__ __forceinline__ s16x8 cvt8(f32x4 a, f32x4 b) {
    s16x8 r;
    r[0] = (short)f2bf(a[0]); r[1] = (short)f2bf(a[1]);
    r[2] = (short)f2bf(a[2]); r[3] = (short)f2bf(a[3]);
    r[4] = (short)f2bf(b[0]); r[5] = (short)f2bf(b[1]);
    r[6] = (short)f2bf(b[2]); r[7] = (short)f2bf(b[3]);
    return r;
}

// ---------------- kernel 1: x fp32 -> bf16, row-major ----------------
__global__ __launch_bounds__(256) void k_convert_x(const float* __restrict__ x,
                                                   unsigned short* __restrict__ xb) {
    int i = (blockIdx.x * 256 + threadIdx.x) * 4;
    f32x4 v = *reinterpret_cast<const f32x4*>(x + i);
    ushort4 o;
    o.x = f2bf(v[0]); o.y = f2bf(v[1]); o.z = f2bf(v[2]); o.w = f2bf(v[3]);
    *reinterpret_cast<ushort4*>(xb + i) = o;
}

// A-tile DMA: 128 rows x 64 bf16 (128 B/row), 16 KB. Block-wide 16 instrs (4/wave).
// XOR(row&7)<<4 pre-swizzle on GLOBAL source; LDS dest linear.
__device__ __forceinline__ void dma_A(const unsigned short* __restrict__ ab, int ldk,
                                      int k0, unsigned short* abuf, int wv, int lane) {
#pragma unroll
    for (int j = 0; j < 4; ++j) {
        int J = wv * 4 + j;                 // 8-row group
        int row = J * 8 + (lane >> 3);
        const unsigned short* src = ab + (size_t)row * ldk + k0 + 8 * ((lane & 7) ^ (lane >> 3));
        __builtin_amdgcn_global_load_lds((as1_u32*)src, (as3_u32*)(abuf + J * 512), 16, 0, 0);
    }
}

// W-tile DMA: 64 rows x 64 f32 (256 B/row), 16 KB. Block-wide 16 instrs (4/wave).
__device__ __forceinline__ void dma_W(const float* __restrict__ w, int ldk, int n0,
                                      int k0, float* wbuf, int wv, int lane) {
#pragma unroll
    for (int j = 0; j < 4; ++j) {
        int R = wv * 16 + j * 4;            // 4-row group
        int row = R + (lane >> 4);
        const float* src = w + (size_t)(n0 + row) * ldk + k0 + 4 * ((lane & 15) ^ (row & 7));
        __builtin_amdgcn_global_load_lds((as1_u32*)src, (as3_u32*)(wbuf + R * 64), 16, 0, 0);
    }
}

// core K-loop: compute reads ONLY LDS; A depth-1, W depth-2 prefetch; counted vmcnt.
template <int LDK>
__device__ __forceinline__ void gemm_core(const unsigned short* __restrict__ ab,
                                          const float* __restrict__ w, int n0,
                                          int sbeg, int send, f32x4 acc[8],
                                          unsigned short* alds, float* wlds) {
    const int tid = threadIdx.x, wv = tid >> 6, lane = tid & 63;
    const int r16 = lane & 15, g4 = lane >> 4;
    const int nst = send - sbeg;

    dma_A(ab, LDK, sbeg * 64, alds, wv, lane);
    dma_W(w, LDK, n0, sbeg * 64, wlds, wv, lane);
    if (nst >= 2) dma_W(w, LDK, n0, (sbeg + 1) * 64, wlds + 4096, wv, lane);

    for (int t = 0; t < nst; ++t) {
        const int s = sbeg + t;
        if (t + 1 < nst) dma_A(ab, LDK, (s + 1) * 64, alds + ((t + 1) & 1) * 8192, wv, lane);
        if (t + 2 < nst) dma_W(w, LDK, n0, (s + 2) * 64, wlds + ((t + 2) % 3) * 4096, wv, lane);
        const int rem = nst - 1 - t;
        if (rem >= 2)      asm volatile("s_waitcnt vmcnt(12)" ::: "memory");
        else if (rem == 1) asm volatile("s_waitcnt vmcnt(8)" ::: "memory");
        else               asm volatile("s_waitcnt vmcnt(0)" ::: "memory");
        __builtin_amdgcn_s_barrier();  // step-t A & W visible block-wide

        const char* wrow = (const char*)(wlds + (t % 3) * 4096) + (wv * 16 + r16) * 256;
        const char* arow = (const char*)(alds + (t & 1) * 8192);
        const unsigned swz = (unsigned)(r16 & 7) << 4;
#pragma unroll
        for (int kk2 = 0; kk2 < 2; ++kk2) {
            unsigned X = kk2 * 128 + g4 * 32;
            f32x4 b0 = *reinterpret_cast<const f32x4*>(wrow + ((X) ^ swz));
            f32x4 b1 = *reinterpret_cast<const f32x4*>(wrow + ((X + 16) ^ swz));
            s16x8 bf = cvt8(b0, b1);
            unsigned ax = (unsigned)(kk2 * 64 + g4 * 16) ^ swz;
#pragma unroll
            for (int mt = 0; mt < 8; ++mt) {
                s16x8 af = *reinterpret_cast<const s16x8*>(arow + (mt * 16 + r16) * 128 + ax);
                acc[mt] = __builtin_amdgcn_mfma_f32_16x16x32_bf16(af, bf, acc[mt], 0, 0, 0);
            }
        }
        __builtin_amdgcn_s_barrier();  // all reads done before next-iter DMA overwrite
    }
}

// ---------------- kernel 2: gate & up GEMM ----------------
// grid.x = 172 * 2 * Sg ; block = 256 (4 waves); block owns 64 weight rows.
__global__ __launch_bounds__(256, 2) void k_gateup6(const unsigned short* __restrict__ xb,
                                                    const float* __restrict__ wg,
                                                    const float* __restrict__ wu,
                                                    float* __restrict__ pg,
                                                    float* __restrict__ pu, int Sg) {
    __shared__ __align__(16) float wlds[3 * 64 * 64];             // 48 KB
    __shared__ __align__(16) unsigned short alds[2 * 128 * 64];   // 32 KB
    const int gid = blockIdx.x;
    const int nt = gid % 172, rest = gid / 172;
    const int mat = rest & 1, kc = rest >> 1;
    const int n0 = nt * 64;
    const int nsteps = 64 / Sg;            // total K-steps = HIDDEN/64 = 64
    const int sbeg = kc * nsteps, send = sbeg + nsteps;

    f32x4 acc[8];
#pragma unroll
    for (int i = 0; i < 8; ++i) acc[i] = (f32x4)0.0f;

    gemm_core<HIDDEN>(xb, mat ? wu : wg, n0, sbeg, send, acc, alds, wlds);

    const int lane = threadIdx.x & 63, wv = threadIdx.x >> 6;
    const int r16 = lane & 15, g4 = lane >> 4;
    float* p = (mat ? pu : pg) + (size_t)kc * (MTOK * INTER);
#pragma unroll
    for (int mt = 0; mt < 8; ++mt)
#pragma unroll
        for (int r = 0; r < 4; ++r) {
            int m = mt * 16 + g4 * 4 + r;
            p[(size_t)m * INTER + n0 + wv * 16 + r16] = acc[mt][r];
        }
}

// ---------------- kernel 3: combine partials + silu*up -> hb (row-major bf16) ----
__global__ __launch_bounds__(256) void k_combine(const float* __restrict__ pg,
                                                 const float* __restrict__ pu,
                                                 unsigned short* __restrict__ hb, int Sg) {
    size_t i = (size_t)(blockIdx.x * 256 + threadIdx.x) * 4;
    f32x4 g = (f32x4)0.0f, u = (f32x4)0.0f;
    for (int c = 0; c < Sg; ++c) {
        g += *reinterpret_cast<const f32x4*>(pg + (size_t)c * (MTOK * INTER) + i);
        u += *reinterpret_cast<const f32x4*>(pu + (size_t)c * (MTOK * INTER) + i);
    }
    ushort4 o;
    o.x = f2bf(g[0] / (1.0f + __expf(-g[0])) * u[0]);
    o.y = f2bf(g[1] / (1.0f + __expf(-g[1])) * u[1]);
    o.z = f2bf(g[2] / (1.0f + __expf(-g[2])) * u[2]);
    o.w = f2bf(g[3] / (1.0f + __expf(-g[3])) * u[3]);
    *reinterpret_cast<ushort4*>(hb + i) = o;
}

// ---------------- kernel 4: down GEMM ----------------
// grid.x = 64 * Sd ; block = 256; K-steps [0,172) split across Sd chunks.
__global__ __launch_bounds__(256, 2) void k_down6(const unsigned short* __restrict__ hb,
                                                  const float* __restrict__ wd,
                                                  float* __restrict__ pd, int Sd) {
    __shared__ __align__(16) float wlds[3 * 64 * 64];
    __shared__ __align__(16) unsigned short alds[2 * 128 * 64];
    const int gid = blockIdx.x;
    const int nt = gid % 64, kc = gid / 64;
    const int n0 = nt * 64;
    const int sbeg = (172 * kc) / Sd, send = (172 * (kc + 1)) / Sd;

    f32x4 acc[8];
#pragma unroll
    for (int i = 0; i < 8; ++i) acc[i] = (f32x4)0.0f;

    gemm_core<INTER>(hb, wd, n0, sbeg, send, acc, alds, wlds);

    const int lane = threadIdx.x & 63, wv = threadIdx.x >> 6;
    const int r16 = lane & 15, g4 = lane >> 4;
    float* p = pd + (size_t)kc * (MTOK * HIDDEN);
#pragma unroll
    for (int mt = 0; mt < 8; ++mt)
#pragma unroll
        for (int r = 0; r < 4; ++r) {
            int m = mt * 16 + g4 * 4 + r;
            p[(size_t)m * HIDDEN + n0 + wv * 16 + r16] = acc[mt][r];
        }
}

// ---------------- kernel 5: reduce Sd partials -> out ----------------
__global__ __launch_bounds__(256) void k_reduce(const float* __restrict__ pd,
                                                float* __restrict__ out, int Sd) {
    int i = (blockIdx.x * 256 + threadIdx.x) * 4;
    const int NT = MTOK * HIDDEN;
    f32x4 s = (f32x4)0.0f;
    for (int c = 0; c < Sd; ++c)
        s += *reinterpret_cast<const f32x4*>(pd + (size_t)c * NT + i);
    *reinterpret_cast<f32x4*>(out + i) = s;
}

extern "C" void kernel_launch(void* const* d_in, const int* in_sizes, int n_in,
                              void* d_out, int out_size, void* d_ws, size_t ws_size,
                              hipStream_t stream) {
    const float* x  = (const float*)d_in[0];
    const float* wg = (const float*)d_in[1];
    const float* wu = (const float*)d_in[2];
    const float* wd = (const float*)d_in[3];
    float* out = (float*)d_out;

    const size_t XB = 1048576;                      // xb row-major bf16
    const size_t HB = 2818048;                      // hb row-major bf16
    const size_t PGU = (size_t)MTOK * INTER * 4;    // per split per matrix
    const size_t PD  = (size_t)MTOK * HIDDEN * 4;   // per split
    const int cfg[4][2] = {{4, 8}, {2, 4}, {1, 2}, {1, 1}};
    int Sg = 1, Sd = 1;
    for (int c = 0; c < 4; ++c) {
        size_t need = XB + HB + 2 * (size_t)cfg[c][0] * PGU + (size_t)cfg[c][1] * PD;
        if (need <= ws_size) { Sg = cfg[c][0]; Sd = cfg[c][1]; break; }
    }

    char* ws = (char*)d_ws;
    unsigned short* xb = (unsigned short*)ws;
    unsigned short* hb = (unsigned short*)(ws + XB);
    float* pg = (float*)(ws + XB + HB);
    float* pu = pg + (size_t)Sg * (MTOK * INTER);
    float* pd = pu + (size_t)Sg * (MTOK * INTER);

    k_convert_x<<<512, 256, 0, stream>>>(x, xb);
    k_gateup6<<<172 * 2 * Sg, 256, 0, stream>>>(xb, wg, wu, pg, pu, Sg);
    k_combine<<<1376, 256, 0, stream>>>(pg, pu, hb, Sg);
    k_down6<<<64 * Sd, 256, 0, stream>>>(hb, wd, pd, Sd);
    k_reduce<<<512, 256, 0, stream>>>(pd, out, Sd);
}

// Round 7
// 176.492 us; speedup vs baseline: 1.9289x; 1.0118x over previous
//
#include <hip/hip_runtime.h>
#include <hip/hip_bf16.h>

#define HIDDEN 4096
#define INTER 11008
#define MTOK 128  // 4*32 tokens

typedef float f32x4 __attribute__((ext_vector_type(4)));
typedef short s16x8 __attribute__((ext_vector_type(8)));

__device__ __forceinline__ unsigned short f2bf(float f) {
    unsigned int u = __float_as_uint(f);
    u += 0x7FFFu + ((u >> 16) & 1u);
    return (unsigned short)(u >> 16);
}

__device__ __forceinline__ s16x8 cvt8(f32x4 a, f32x4 b) {
    s16x8 r;
    r[0] = (short)f2bf(a[0]); r[1] = (short)f2bf(a[1]);
    r[2] = (short)f2bf(a[2]); r[3] = (short)f2bf(a[3]);
    r[4] = (short)f2bf(b[0]); r[5] = (short)f2bf(b[1]);
    r[6] = (short)f2bf(b[2]); r[7] = (short)f2bf(b[3]);
    return r;
}

// ---------- kernel 0: calibration probe — sequential stream of wg ----------
__global__ __launch_bounds__(256) void k_probe(const float* __restrict__ wg,
                                               float* __restrict__ sink) {
    const int NF = INTER * HIDDEN;  // 45,088,768 floats
    int tid = blockIdx.x * 256 + threadIdx.x;
    f32x4 s = (f32x4)0.0f;
    for (int i = tid * 4; i < NF; i += 2048 * 256 * 4)
        s += *reinterpret_cast<const f32x4*>(wg + i);
    sink[tid] = s[0] + s[1] + s[2] + s[3];  // overwritten later by gateup
}

// ---------- kernel 1: x fp32 -> bf16 in MFMA FRAGMENT ORDER ----------
// Group g = ((s64*8 + mt)*2 + kk2)*64 + lane holds 8 bf16 of
//   x[mt*16 + (lane&15)][s64*64 + kk2*32 + (lane>>4)*8 + e]
__global__ __launch_bounds__(256) void k_convert_x2(const float* __restrict__ x,
                                                    s16x8* __restrict__ xf) {
    int t = blockIdx.x * 256 + threadIdx.x;  // [0, 65536)
    int lane = t & 63, kk2 = (t >> 6) & 1, mt = (t >> 7) & 7, s64 = t >> 10;
    int row = mt * 16 + (lane & 15);
    int k0 = s64 * 64 + kk2 * 32 + (lane >> 4) * 8;
    const float* p = x + (size_t)row * HIDDEN + k0;
    f32x4 a = *reinterpret_cast<const f32x4*>(p);
    f32x4 b = *reinterpret_cast<const f32x4*>(p + 4);
    xf[t] = cvt8(a, b);
}

// ---------- shared GEMM pieces (K_STEP = 128) ----------
// A-frags: 16 per buffer (4 mt x 4 kk), from frag-ordered buffer, all coalesced.
__device__ __forceinline__ void loadA(const s16x8* __restrict__ afb, int wr, int s,
                                      int lane, s16x8 a[16]) {
#pragma unroll
    for (int kk = 0; kk < 4; ++kk)
#pragma unroll
        for (int mi = 0; mi < 4; ++mi) {
            int mt = wr * 4 + mi;
            int s64 = s * 2 + (kk >> 1), kk2 = kk & 1;
            a[kk * 4 + mi] = afb[(size_t)(((s64 * 8 + mt) * 2 + kk2) * 64 + lane)];
        }
}

// W: 16 rows/wave, 512 B contiguous per row per instr (2 rows per instr).
__device__ __forceinline__ void loadW(const float* __restrict__ w, int ldk, int n0,
                                      int wv, int lane, int s, f32x4 r[8]) {
    const int k0 = s * 128 + (lane & 31) * 4;
    const int rbase = n0 + wv * 16 + (lane >> 5);
#pragma unroll
    for (int j = 0; j < 8; ++j)
        r[j] = *reinterpret_cast<const f32x4*>(w + (size_t)(rbase + j * 2) * ldk + k0);
}

// cvt fp32->bf16 and write to LDS with XOR(row&7)<<4 swizzle (write side).
__device__ __forceinline__ void writeW(char* wb, int wv, int lane, const f32x4 r[8]) {
    const int l5 = lane >> 5, c = lane & 31;
#pragma unroll
    for (int j = 0; j < 8; ++j) {
        int row = wv * 16 + j * 2 + l5;
        ushort4 o;
        o.x = f2bf(r[j][0]); o.y = f2bf(r[j][1]);
        o.z = f2bf(r[j][2]); o.w = f2bf(r[j][3]);
        *reinterpret_cast<ushort4*>(wb + ((row * 256 + c * 8) ^ ((row & 7) << 4))) = o;
    }
}

// compute: 8 swizzled b128 LDS reads + 32 MFMA per wave.
__device__ __forceinline__ void comp(const char* wb, int wc, int lane,
                                     const s16x8 a[16], f32x4 acc[4][2]) {
    const int r16 = lane & 15, g4 = lane >> 4;
#pragma unroll
    for (int nf = 0; nf < 2; ++nf) {
        int row = wc * 32 + nf * 16 + r16;
        const char* wrp = wb + row * 256;
        unsigned swz = (unsigned)((row & 7) << 4);
#pragma unroll
        for (int kk = 0; kk < 4; ++kk) {
            s16x8 bf = *reinterpret_cast<const s16x8*>(wrp + ((unsigned)(kk * 64 + g4 * 16) ^ swz));
#pragma unroll
            for (int mi = 0; mi < 4; ++mi)
                acc[mi][nf] = __builtin_amdgcn_mfma_f32_16x16x32_bf16(a[kk * 4 + mi], bf,
                                                                      acc[mi][nf], 0, 0, 0);
        }
    }
}

template <int LDK>
__device__ __forceinline__ void gemm7(const s16x8* __restrict__ afb,
                                      const float* __restrict__ w, int n0,
                                      int sbeg, int nsteps, int phase,
                                      f32x4 acc[4][2], char* wb) {
    const int tid = threadIdx.x, wv = tid >> 6, lane = tid & 63;
    const int wr = wv >> 1, wc = wv & 1;
    s16x8 aA[16], aB[16];
    f32x4 rw[8];

    loadA(afb, wr, sbeg + phase, lane, aA);
    loadW(w, LDK, n0, wv, lane, sbeg + phase, rw);
    writeW(wb, wv, lane, rw);
    __syncthreads();

    for (int tt = 0; tt < nsteps; tt += 2) {
        {   // even step: A in aA, W in wb[0]
            if (tt + 1 < nsteps) {
                int sn = sbeg + (tt + 1 + phase) % nsteps;
                loadW(w, LDK, n0, wv, lane, sn, rw);
                loadA(afb, wr, sn, lane, aB);
            }
            comp(wb, wc, lane, aA, acc);
            if (tt + 1 < nsteps) writeW(wb + 16384, wv, lane, rw);
            __syncthreads();
        }
        if (tt + 1 < nsteps) {  // odd step: A in aB, W in wb[1]
            if (tt + 2 < nsteps) {
                int sn = sbeg + (tt + 2 + phase) % nsteps;
                loadW(w, LDK, n0, wv, lane, sn, rw);
                loadA(afb, wr, sn, lane, aA);
            }
            comp(wb + 16384, wc, lane, aB, acc);
            if (tt + 2 < nsteps) writeW(wb, wv, lane, rw);
            __syncthreads();
        }
    }
}

// ---------- kernel 2: gate & up GEMM ----------
// grid.x = 172 * 2 * Sg ; block = 256 (4 waves, 2x2), N_tile = 64 rows.
__global__ __launch_bounds__(256, 2) void k_gateup7(const s16x8* __restrict__ xf,
                                                    const float* __restrict__ wg,
                                                    const float* __restrict__ wu,
                                                    float* __restrict__ pg,
                                                    float* __restrict__ pu, int Sg) {
    __shared__ __align__(16) char wb[2 * 16384];  // 32 KB (2 x 64 rows x 128 bf16)
    const int gid = blockIdx.x;
    const int nt = gid % 172, rest = gid / 172;
    const int mat = rest & 1, kc = rest >> 1;
    const int n0 = nt * 64;
    const int nsteps = 32 / Sg;                   // K-steps of 128; total 32
    const int sbeg = kc * nsteps;
    const int phase = (gid * 5) % nsteps;

    f32x4 acc[4][2] = {};
    gemm7<HIDDEN>(xf, mat ? wu : wg, n0, sbeg, nsteps, phase, acc, wb);

    const int lane = threadIdx.x & 63, wv = threadIdx.x >> 6;
    const int wr = wv >> 1, wc = wv & 1;
    const int r16 = lane & 15, g4 = lane >> 4;
    float* p = (mat ? pu : pg) + (size_t)kc * (MTOK * INTER);
#pragma unroll
    for (int mi = 0; mi < 4; ++mi)
#pragma unroll
        for (int nf = 0; nf < 2; ++nf)
#pragma unroll
            for (int r = 0; r < 4; ++r) {
                int m = (wr * 4 + mi) * 16 + g4 * 4 + r;
                p[(size_t)m * INTER + n0 + wc * 32 + nf * 16 + r16] = acc[mi][nf][r];
            }
}

// ---------- kernel 3: combine + silu*up -> h in FRAG ORDER (bf16) ----------
__global__ __launch_bounds__(256) void k_combine2(const float* __restrict__ pg,
                                                  const float* __restrict__ pu,
                                                  s16x8* __restrict__ hf, int Sg) {
    int t = blockIdx.x * 256 + threadIdx.x;  // [0, 176128)
    int lane = t & 63, r16 = lane & 15, g4 = (lane >> 4) & 3;
    int kk2 = (t >> 6) & 1, mt = (t >> 7) & 7, s64 = t >> 10;
    int m = mt * 16 + r16;
    size_t base = (size_t)m * INTER + s64 * 64 + kk2 * 32 + g4 * 8;

    f32x4 g0 = (f32x4)0.0f, g1 = (f32x4)0.0f, u0 = (f32x4)0.0f, u1 = (f32x4)0.0f;
    for (int c = 0; c < Sg; ++c) {
        const float* pgc = pg + (size_t)c * (MTOK * INTER) + base;
        const float* puc = pu + (size_t)c * (MTOK * INTER) + base;
        g0 += *reinterpret_cast<const f32x4*>(pgc);
        g1 += *reinterpret_cast<const f32x4*>(pgc + 4);
        u0 += *reinterpret_cast<const f32x4*>(puc);
        u1 += *reinterpret_cast<const f32x4*>(puc + 4);
    }
    f32x4 h0, h1;
#pragma unroll
    for (int e = 0; e < 4; ++e) {
        h0[e] = g0[e] / (1.0f + __expf(-g0[e])) * u0[e];
        h1[e] = g1[e] / (1.0f + __expf(-g1[e])) * u1[e];
    }
    hf[t] = cvt8(h0, h1);
}

// ---------- kernel 4: down GEMM ----------
// grid.x = 64 * Sd ; block = 256. K-steps [0,86) split across Sd chunks.
__global__ __launch_bounds__(256, 2) void k_down7(const s16x8* __restrict__ hf,
                                                  const float* __restrict__ wd,
                                                  float* __restrict__ pd, int Sd) {
    __shared__ __align__(16) char wb[2 * 16384];
    const int gid = blockIdx.x;
    const int nt = gid % 64, kc = gid / 64;
    const int n0 = nt * 64;
    const int sbeg = (86 * kc) / Sd, send = (86 * (kc + 1)) / Sd;
    const int nsteps = send - sbeg;
    const int phase = (gid * 5) % nsteps;

    f32x4 acc[4][2] = {};
    gemm7<INTER>(hf, wd, n0, sbeg, nsteps, phase, acc, wb);

    const int lane = threadIdx.x & 63, wv = threadIdx.x >> 6;
    const int wr = wv >> 1, wc = wv & 1;
    const int r16 = lane & 15, g4 = lane >> 4;
    float* p = pd + (size_t)kc * (MTOK * HIDDEN);
#pragma unroll
    for (int mi = 0; mi < 4; ++mi)
#pragma unroll
        for (int nf = 0; nf < 2; ++nf)
#pragma unroll
            for (int r = 0; r < 4; ++r) {
                int m = (wr * 4 + mi) * 16 + g4 * 4 + r;
                p[(size_t)m * HIDDEN + n0 + wc * 32 + nf * 16 + r16] = acc[mi][nf][r];
            }
}

// ---------- kernel 5: reduce Sd partials -> out ----------
__global__ __launch_bounds__(256) void k_reduce(const float* __restrict__ pd,
                                                float* __restrict__ out, int Sd) {
    int i = (blockIdx.x * 256 + threadIdx.x) * 4;
    const int NT = MTOK * HIDDEN;
    f32x4 s = (f32x4)0.0f;
    for (int c = 0; c < Sd; ++c)
        s += *reinterpret_cast<const f32x4*>(pd + (size_t)c * NT + i);
    *reinterpret_cast<f32x4*>(out + i) = s;
}

extern "C" void kernel_launch(void* const* d_in, const int* in_sizes, int n_in,
                              void* d_out, int out_size, void* d_ws, size_t ws_size,
                              hipStream_t stream) {
    const float* x  = (const float*)d_in[0];
    const float* wg = (const float*)d_in[1];
    const float* wu = (const float*)d_in[2];
    const float* wd = (const float*)d_in[3];
    float* out = (float*)d_out;

    const size_t XB = 1048576;                      // xf frag-ordered bf16
    const size_t HB = 2818048;                      // hf frag-ordered bf16
    const size_t PGU = (size_t)MTOK * INTER * 4;    // per split per matrix
    const size_t PD  = (size_t)MTOK * HIDDEN * 4;   // per split
    const int cfg[4][2] = {{4, 8}, {2, 8}, {2, 4}, {1, 2}};
    int Sg = 1, Sd = 2;
    for (int c = 0; c < 4; ++c) {
        size_t need = XB + HB + 2 * (size_t)cfg[c][0] * PGU + (size_t)cfg[c][1] * PD;
        if (need <= ws_size) { Sg = cfg[c][0]; Sd = cfg[c][1]; break; }
    }

    char* ws = (char*)d_ws;
    s16x8* xf = (s16x8*)ws;
    s16x8* hf = (s16x8*)(ws + XB);
    float* pg = (float*)(ws + XB + HB);
    float* pu = pg + (size_t)Sg * (MTOK * INTER);
    float* pd = pu + (size_t)Sg * (MTOK * INTER);

    k_probe<<<2048, 256, 0, stream>>>(wg, pg);      // calibration; pg overwritten below
    k_convert_x2<<<256, 256, 0, stream>>>(x, xf);
    k_gateup7<<<172 * 2 * Sg, 256, 0, stream>>>(xf, wg, wu, pg, pu, Sg);
    k_combine2<<<688, 256, 0, stream>>>(pg, pu, hf, Sg);
    k_down7<<<64 * Sd, 256, 0, stream>>>(hf, wd, pd, Sd);
    k_reduce<<<512, 256, 0, stream>>>(pd, out, Sd);
}

// Round 8
// 152.228 us; speedup vs baseline: 2.2363x; 1.1594x over previous
//
#include <hip/hip_runtime.h>
#include <hip/hip_bf16.h>

#define HIDDEN 4096
#define INTER 11008
#define MTOK 128  // 4*32 tokens

typedef float f32x4 __attribute__((ext_vector_type(4)));
typedef short s16x8 __attribute__((ext_vector_type(8)));

__device__ __forceinline__ unsigned short f2bf(float f) {
    unsigned int u = __float_as_uint(f);
    u += 0x7FFFu + ((u >> 16) & 1u);
    return (unsigned short)(u >> 16);
}

__device__ __forceinline__ s16x8 cvt8(f32x4 a, f32x4 b) {
    s16x8 r;
    r[0] = (short)f2bf(a[0]); r[1] = (short)f2bf(a[1]);
    r[2] = (short)f2bf(a[2]); r[3] = (short)f2bf(a[3]);
    r[4] = (short)f2bf(b[0]); r[5] = (short)f2bf(b[1]);
    r[6] = (short)f2bf(b[2]); r[7] = (short)f2bf(b[3]);
    return r;
}

// ---------- kernel 1: x fp32 -> bf16 in MFMA FRAGMENT ORDER ----------
// Group g = ((s64*8 + mt)*2 + kk2)*64 + lane holds 8 bf16 of
//   x[mt*16 + (lane&15)][s64*64 + kk2*32 + (lane>>4)*8 + e]
__global__ __launch_bounds__(256) void k_convert_x2(const float* __restrict__ x,
                                                    s16x8* __restrict__ xf) {
    int t = blockIdx.x * 256 + threadIdx.x;  // [0, 65536)
    int lane = t & 63, kk2 = (t >> 6) & 1, mt = (t >> 7) & 7, s64 = t >> 10;
    int row = mt * 16 + (lane & 15);
    int k0 = s64 * 64 + kk2 * 32 + (lane >> 4) * 8;
    const float* p = x + (size_t)row * HIDDEN + k0;
    f32x4 a = *reinterpret_cast<const f32x4*>(p);
    f32x4 b = *reinterpret_cast<const f32x4*>(p + 4);
    xf[t] = cvt8(a, b);
}

// ---------- GEMM building blocks, K_STEP = 256 ----------
// A: 16 frags (2 mt x 8 kk) from frag-ordered buffer; all 1KB-coalesced loads.
__device__ __forceinline__ void loadA8(const s16x8* __restrict__ afb, int mt0, int s,
                                       int lane, s16x8 a[16]) {
#pragma unroll
    for (int kk = 0; kk < 8; ++kk)
#pragma unroll
        for (int mi = 0; mi < 2; ++mi) {
            int s64 = s * 4 + (kk >> 1), kk2 = kk & 1;
            a[kk * 2 + mi] = afb[(size_t)(((s64 * 8 + mt0 + mi) * 2 + kk2) * 64 + lane)];
        }
}

// W: 16 rows x 1KB fp32; ONE full-wave dwordx4 instr per row (1KB contiguous/visit).
template <int LDK>
__device__ __forceinline__ void loadW16(const float* __restrict__ w, int row0,
                                        int lane, int s, f32x4 r[16]) {
    const float* base = w + (size_t)row0 * LDK + s * 256 + lane * 4;
#pragma unroll
    for (int j = 0; j < 16; ++j)
        r[j] = *reinterpret_cast<const f32x4*>(base + (size_t)j * LDK);
}

// cvt fp32->bf16, write to LDS rows of 512B with XOR(row&7)<<4 swizzle.
__device__ __forceinline__ void writeW16(char* wb, int wv, int lane, const f32x4 r[16]) {
#pragma unroll
    for (int j = 0; j < 16; ++j) {
        int row = wv * 16 + j;
        ushort4 o;
        o.x = f2bf(r[j][0]); o.y = f2bf(r[j][1]);
        o.z = f2bf(r[j][2]); o.w = f2bf(r[j][3]);
        *reinterpret_cast<ushort4*>(wb + row * 512 + ((lane * 8) ^ ((row & 7) << 4))) = o;
    }
}

// compute: wave = 2 mt x 64 cols x K=256 -> 64 MFMA, 32 swizzled b128 LDS reads.
__device__ __forceinline__ void comp8(const char* wb, int lane, const s16x8 a[16],
                                      f32x4 acc[2][4]) {
    const int r16 = lane & 15, g4 = lane >> 4;
#pragma unroll
    for (int nf = 0; nf < 4; ++nf) {
        int row = nf * 16 + r16;
        const char* wrp = wb + row * 512;
        unsigned swz = (unsigned)((row & 7) << 4);
#pragma unroll
        for (int kk = 0; kk < 8; ++kk) {
            s16x8 bf = *reinterpret_cast<const s16x8*>(wrp + ((unsigned)(kk * 64 + g4 * 16) ^ swz));
#pragma unroll
            for (int mi = 0; mi < 2; ++mi)
                acc[mi][nf] = __builtin_amdgcn_mfma_f32_16x16x32_bf16(a[kk * 2 + mi], bf,
                                                                      acc[mi][nf], 0, 0, 0);
        }
    }
}

template <int LDK>
__device__ __forceinline__ void gemm8(const s16x8* __restrict__ afb,
                                      const float* __restrict__ w, int n0,
                                      int sbeg, int send, f32x4 acc[2][4], char* wb) {
    const int tid = threadIdx.x, wv = tid >> 6, lane = tid & 63;
    const int mt0 = wv * 2;
    s16x8 a[16];
    f32x4 rw[16];

    loadW16<LDK>(w, n0 + wv * 16, lane, sbeg, rw);
    writeW16(wb, wv, lane, rw);
    __syncthreads();

    for (int s = sbeg; s < send; ++s) {
        const int buf = (s - sbeg) & 1;
        loadA8(afb, mt0, s, lane, a);                       // A(t) issued FIRST
        __builtin_amdgcn_sched_barrier(0);
        if (s + 1 < send) loadW16<LDK>(w, n0 + wv * 16, lane, s + 1, rw);  // W(t+1) younger
        __builtin_amdgcn_sched_barrier(0);
        comp8(wb + buf * 32768, lane, a, acc);              // waits A (counted), W in flight
        __builtin_amdgcn_sched_barrier(0);
        if (s + 1 < send) writeW16(wb + (buf ^ 1) * 32768, wv, lane, rw);  // drains W
        __syncthreads();
    }
}

// ---------- kernel 2: gate & up GEMM ----------
// grid.x = 172 * 2 * Sg ; block = 256 (4 waves); N_tile = 64 weight rows.
__global__ __launch_bounds__(256, 2) void k_gateup8(const s16x8* __restrict__ xf,
                                                    const float* __restrict__ wg,
                                                    const float* __restrict__ wu,
                                                    float* __restrict__ pg,
                                                    float* __restrict__ pu, int Sg) {
    __shared__ __align__(16) char wb[2 * 32768];  // 64 KB
    const int gid = blockIdx.x;
    const int nt = gid % 172, rest = gid / 172;
    const int mat = rest & 1, kc = rest >> 1;
    const int n0 = nt * 64;
    const int nsteps = 16 / Sg;                   // K-steps of 256; total 16
    const int sbeg = kc * nsteps, send = sbeg + nsteps;

    f32x4 acc[2][4] = {};
    gemm8<HIDDEN>(xf, mat ? wu : wg, n0, sbeg, send, acc, wb);

    const int lane = threadIdx.x & 63, wv = threadIdx.x >> 6;
    const int r16 = lane & 15, g4 = lane >> 4;
    float* p = (mat ? pu : pg) + (size_t)kc * (MTOK * INTER);
#pragma unroll
    for (int mi = 0; mi < 2; ++mi)
#pragma unroll
        for (int nf = 0; nf < 4; ++nf)
#pragma unroll
            for (int r = 0; r < 4; ++r) {
                int m = (wv * 2 + mi) * 16 + g4 * 4 + r;
                p[(size_t)m * INTER + n0 + nf * 16 + r16] = acc[mi][nf][r];
            }
}

// ---------- kernel 3: combine + silu*up -> h in FRAG ORDER (bf16) ----------
__global__ __launch_bounds__(256) void k_combine2(const float* __restrict__ pg,
                                                  const float* __restrict__ pu,
                                                  s16x8* __restrict__ hf, int Sg) {
    int t = blockIdx.x * 256 + threadIdx.x;  // [0, 176128)
    int lane = t & 63, r16 = lane & 15, g4 = (lane >> 4) & 3;
    int kk2 = (t >> 6) & 1, mt = (t >> 7) & 7, s64 = t >> 10;
    int m = mt * 16 + r16;
    size_t base = (size_t)m * INTER + s64 * 64 + kk2 * 32 + g4 * 8;

    f32x4 g0 = (f32x4)0.0f, g1 = (f32x4)0.0f, u0 = (f32x4)0.0f, u1 = (f32x4)0.0f;
    for (int c = 0; c < Sg; ++c) {
        const float* pgc = pg + (size_t)c * (MTOK * INTER) + base;
        const float* puc = pu + (size_t)c * (MTOK * INTER) + base;
        g0 += *reinterpret_cast<const f32x4*>(pgc);
        g1 += *reinterpret_cast<const f32x4*>(pgc + 4);
        u0 += *reinterpret_cast<const f32x4*>(puc);
        u1 += *reinterpret_cast<const f32x4*>(puc + 4);
    }
    f32x4 h0, h1;
#pragma unroll
    for (int e = 0; e < 4; ++e) {
        h0[e] = g0[e] / (1.0f + __expf(-g0[e])) * u0[e];
        h1[e] = g1[e] / (1.0f + __expf(-g1[e])) * u1[e];
    }
    hf[t] = cvt8(h0, h1);
}

// ---------- kernel 4: down GEMM ----------
// grid.x = 64 * Sd ; block = 256. K-steps [0,43) of 256 split across Sd chunks.
__global__ __launch_bounds__(256, 2) void k_down8(const s16x8* __restrict__ hf,
                                                  const float* __restrict__ wd,
                                                  float* __restrict__ pd, int Sd) {
    __shared__ __align__(16) char wb[2 * 32768];
    const int gid = blockIdx.x;
    const int nt = gid % 64, kc = gid / 64;
    const int n0 = nt * 64;
    const int sbeg = (43 * kc) / Sd, send = (43 * (kc + 1)) / Sd;

    f32x4 acc[2][4] = {};
    gemm8<INTER>(hf, wd, n0, sbeg, send, acc, wb);

    const int lane = threadIdx.x & 63, wv = threadIdx.x >> 6;
    const int r16 = lane & 15, g4 = lane >> 4;
    float* p = pd + (size_t)kc * (MTOK * HIDDEN);
#pragma unroll
    for (int mi = 0; mi < 2; ++mi)
#pragma unroll
        for (int nf = 0; nf < 4; ++nf)
#pragma unroll
            for (int r = 0; r < 4; ++r) {
                int m = (wv * 2 + mi) * 16 + g4 * 4 + r;
                p[(size_t)m * HIDDEN + n0 + nf * 16 + r16] = acc[mi][nf][r];
            }
}

// ---------- kernel 5: reduce Sd partials -> out ----------
__global__ __launch_bounds__(256) void k_reduce(const float* __restrict__ pd,
                                                float* __restrict__ out, int Sd) {
    int i = (blockIdx.x * 256 + threadIdx.x) * 4;
    const int NT = MTOK * HIDDEN;
    f32x4 s = (f32x4)0.0f;
    for (int c = 0; c < Sd; ++c)
        s += *reinterpret_cast<const f32x4*>(pd + (size_t)c * NT + i);
    *reinterpret_cast<f32x4*>(out + i) = s;
}

extern "C" void kernel_launch(void* const* d_in, const int* in_sizes, int n_in,
                              void* d_out, int out_size, void* d_ws, size_t ws_size,
                              hipStream_t stream) {
    const float* x  = (const float*)d_in[0];
    const float* wg = (const float*)d_in[1];
    const float* wu = (const float*)d_in[2];
    const float* wd = (const float*)d_in[3];
    float* out = (float*)d_out;

    const size_t XB = 1048576;                      // xf frag-ordered bf16
    const size_t HB = 2818048;                      // hf frag-ordered bf16
    const size_t PGU = (size_t)MTOK * INTER * 4;    // per split per matrix
    const size_t PD  = (size_t)MTOK * HIDDEN * 4;   // per split
    const int cfg[4][2] = {{2, 8}, {1, 4}, {1, 2}, {1, 1}};
    int Sg = 1, Sd = 1;
    for (int c = 0; c < 4; ++c) {
        size_t need = XB + HB + 2 * (size_t)cfg[c][0] * PGU + (size_t)cfg[c][1] * PD;
        if (need <= ws_size) { Sg = cfg[c][0]; Sd = cfg[c][1]; break; }
    }

    char* ws = (char*)d_ws;
    s16x8* xf = (s16x8*)ws;
    s16x8* hf = (s16x8*)(ws + XB);
    float* pg = (float*)(ws + XB + HB);
    float* pu = pg + (size_t)Sg * (MTOK * INTER);
    float* pd = pu + (size_t)Sg * (MTOK * INTER);

    k_convert_x2<<<256, 256, 0, stream>>>(x, xf);
    k_gateup8<<<172 * 2 * Sg, 256, 0, stream>>>(xf, wg, wu, pg, pu, Sg);
    k_combine2<<<688, 256, 0, stream>>>(pg, pu, hf, Sg);
    k_down8<<<64 * Sd, 256, 0, stream>>>(hf, wd, pd, Sd);
    k_reduce<<<512, 256, 0, stream>>>(pd, out, Sd);
}